// Round 1
// baseline (89.823 us; speedup 1.0000x reference)
//
#include <hip/hip_runtime.h>

#define HH 1024
#define WW 1024
#define NR 16                          // output rows per block
#define STRIPS (HH / NR)               // 64 strips per image
#define NBLK (32 * STRIPS)             // 2048 blocks

__device__ __forceinline__ float4 ldrow(const float* __restrict__ img, int y, int t) {
    return reinterpret_cast<const float4*>(img + (size_t)y * WW)[t];
}

__global__ __launch_bounds__(256) void sobel_loss_kernel(
    const float* __restrict__ fake, const float* __restrict__ real,
    double* __restrict__ acc_num, unsigned long long* __restrict__ acc_cnt)
{
    const int t  = threadIdx.x;
    const int b  = blockIdx.x / STRIPS;
    const int y0 = (blockIdx.x % STRIPS) * NR;
    const float* fimg = fake + (size_t)b * HH * WW;
    const float* rimg = real + (size_t)b * HH * WW;

    // boundary-exchange arrays (stride-1 access: conflict-free)
    __shared__ float sfL[256], sfR[256], srL[256], srR[256];

    float4 fprev = ldrow(fimg, max(y0 - 1, 0), t);
    float4 fcur  = ldrow(fimg, y0, t);
    float4 rprev = ldrow(rimg, max(y0 - 1, 0), t);
    float4 rcur  = ldrow(rimg, y0, t);

    float num = 0.f;
    int   cnt = 0;

    for (int i = 0; i < NR; ++i) {
        const int y  = y0 + i;
        const int yn = min(y + 1, HH - 1);
        float4 fnext = ldrow(fimg, yn, t);
        float4 rnext = ldrow(rimg, yn, t);

        // vertical smooth S = prev + 2*cur + next  (matches jax op order)
        float4 Sf, Sr;
        Sf.x = fprev.x + 2.f * fcur.x + fnext.x;
        Sf.y = fprev.y + 2.f * fcur.y + fnext.y;
        Sf.z = fprev.z + 2.f * fcur.z + fnext.z;
        Sf.w = fprev.w + 2.f * fcur.w + fnext.w;
        Sr.x = rprev.x + 2.f * rcur.x + rnext.x;
        Sr.y = rprev.y + 2.f * rcur.y + rnext.y;
        Sr.z = rprev.z + 2.f * rcur.z + rnext.z;
        Sr.w = rprev.w + 2.f * rcur.w + rnext.w;

        sfL[t] = Sf.x; sfR[t] = Sf.w;
        srL[t] = Sr.x; srR[t] = Sr.w;
        __syncthreads();

        // neighbors: S[x0-1] from thread t-1's right, S[x0+4] from t+1's left.
        // Edge clamp (x=0 / x=1023) folds to using own .x / .w.
        const float fm = (t == 0)   ? Sf.x : sfR[t - 1];
        const float fp = (t == 255) ? Sf.w : sfL[t + 1];
        const float rm = (t == 0)   ? Sr.x : srR[t - 1];
        const float rp = (t == 255) ? Sr.w : srL[t + 1];

        float ef, er;
        er = Sr.y - rm;   ef = Sf.y - fm;   if (er > 0.f) { num += fabsf(ef - er); ++cnt; }
        er = Sr.z - Sr.x; ef = Sf.z - Sf.x; if (er > 0.f) { num += fabsf(ef - er); ++cnt; }
        er = Sr.w - Sr.y; ef = Sf.w - Sf.y; if (er > 0.f) { num += fabsf(ef - er); ++cnt; }
        er = rp - Sr.z;   ef = fp - Sf.z;   if (er > 0.f) { num += fabsf(ef - er); ++cnt; }

        __syncthreads();   // protect boundary arrays before next iteration's writes

        fprev = fcur; fcur = fnext;
        rprev = rcur; rcur = rnext;
    }

    // wave64 reduce
    for (int off = 32; off; off >>= 1) {
        num += __shfl_down(num, off);
        cnt += __shfl_down(cnt, off);
    }
    __shared__ float wnum[4];
    __shared__ int   wcnt[4];
    const int wave = t >> 6, lane = t & 63;
    if (lane == 0) { wnum[wave] = num; wcnt[wave] = cnt; }
    __syncthreads();
    if (t == 0) {
        const float n = wnum[0] + wnum[1] + wnum[2] + wnum[3];
        const int   c = wcnt[0] + wcnt[1] + wcnt[2] + wcnt[3];
        atomicAdd(acc_num, (double)n);
        atomicAdd(acc_cnt, (unsigned long long)c);
    }
}

__global__ void finalize_kernel(const double* __restrict__ acc_num,
                                const unsigned long long* __restrict__ acc_cnt,
                                float* __restrict__ out)
{
    const double c = (double)(*acc_cnt);
    out[0] = (float)((*acc_num) / c / 32.0);
}

extern "C" void kernel_launch(void* const* d_in, const int* in_sizes, int n_in,
                              void* d_out, int out_size, void* d_ws, size_t ws_size,
                              hipStream_t stream)
{
    const float* fake = (const float*)d_in[0];
    const float* real = (const float*)d_in[1];
    float* out = (float*)d_out;

    double* acc_num             = (double*)d_ws;
    unsigned long long* acc_cnt = (unsigned long long*)((char*)d_ws + 8);

    hipMemsetAsync(d_ws, 0, 16, stream);
    sobel_loss_kernel<<<NBLK, 256, 0, stream>>>(fake, real, acc_num, acc_cnt);
    finalize_kernel<<<1, 1, 0, stream>>>(acc_num, acc_cnt, out);
}

// Round 2
// 83.735 us; speedup vs baseline: 1.0727x; 1.0727x over previous
//
#include <hip/hip_runtime.h>

#define HH 1024
#define WW 1024
#define NR 16                          // output rows per block
#define STRIPS (HH / NR)               // 64 strips per image
#define NBLK (32 * STRIPS)             // 2048 blocks

struct Row { float l; float4 v; float r; };

__device__ __forceinline__ Row ldrow(const float* __restrict__ img, int y,
                                     int x0, int xl, int xr) {
    const float* p = img + (size_t)y * WW;
    Row r;
    r.v = *reinterpret_cast<const float4*>(p + x0);
    r.l = p[xl];                        // clamped halo: hits neighbor's cache line
    r.r = p[xr];
    return r;
}

__global__ __launch_bounds__(256) void sobel_loss_kernel(
    const float* __restrict__ fake, const float* __restrict__ real,
    double* __restrict__ acc_num, unsigned long long* __restrict__ acc_cnt)
{
    const int t  = threadIdx.x;
    const int b  = blockIdx.x / STRIPS;
    const int y0 = (blockIdx.x % STRIPS) * NR;
    const float* fimg = fake + (size_t)b * HH * WW;
    const float* rimg = real + (size_t)b * HH * WW;

    const int x0 = 4 * t;
    const int xl = max(x0 - 1, 0);          // clamp -> edge replicate
    const int xr = min(x0 + 4, WW - 1);

    Row fp_ = ldrow(fimg, max(y0 - 1, 0), x0, xl, xr);
    Row fc_ = ldrow(fimg, y0,             x0, xl, xr);
    Row rp_ = ldrow(rimg, max(y0 - 1, 0), x0, xl, xr);
    Row rc_ = ldrow(rimg, y0,             x0, xl, xr);

    float num = 0.f;
    int   cnt = 0;

    #pragma unroll
    for (int i = 0; i < NR; ++i) {
        const int yn = min(y0 + i + 1, HH - 1);
        Row fn_ = ldrow(fimg, yn, x0, xl, xr);
        Row rn_ = ldrow(rimg, yn, x0, xl, xr);

        // vertical smooth S = prev + 2*cur + next (same FP order as jax)
        float  fSm = fp_.l   + 2.f * fc_.l   + fn_.l;
        float  rSm = rp_.l   + 2.f * rc_.l   + rn_.l;
        float4 fS, rS;
        fS.x = fp_.v.x + 2.f * fc_.v.x + fn_.v.x;
        fS.y = fp_.v.y + 2.f * fc_.v.y + fn_.v.y;
        fS.z = fp_.v.z + 2.f * fc_.v.z + fn_.v.z;
        fS.w = fp_.v.w + 2.f * fc_.v.w + fn_.v.w;
        rS.x = rp_.v.x + 2.f * rc_.v.x + rn_.v.x;
        rS.y = rp_.v.y + 2.f * rc_.v.y + rn_.v.y;
        rS.z = rp_.v.z + 2.f * rc_.v.z + rn_.v.z;
        rS.w = rp_.v.w + 2.f * rc_.v.w + rn_.v.w;
        float  fSp = fp_.r   + 2.f * fc_.r   + fn_.r;
        float  rSp = rp_.r   + 2.f * rc_.r   + rn_.r;

        // e[x] = S[clamp(x+1)] - S[clamp(x-1)]; clamped loads make edges exact
        float ef, er;
        er = rS.y - rSm;  ef = fS.y - fSm;  if (er > 0.f) { num += fabsf(ef - er); ++cnt; }
        er = rS.z - rS.x; ef = fS.z - fS.x; if (er > 0.f) { num += fabsf(ef - er); ++cnt; }
        er = rS.w - rS.y; ef = fS.w - fS.y; if (er > 0.f) { num += fabsf(ef - er); ++cnt; }
        er = rSp - rS.z;  ef = fSp - fS.z;  if (er > 0.f) { num += fabsf(ef - er); ++cnt; }

        fp_ = fc_; fc_ = fn_;
        rp_ = rc_; rc_ = rn_;
    }

    // wave64 reduce, then one atomic per block
    for (int off = 32; off; off >>= 1) {
        num += __shfl_down(num, off);
        cnt += __shfl_down(cnt, off);
    }
    __shared__ float wnum[4];
    __shared__ int   wcnt[4];
    const int wave = t >> 6, lane = t & 63;
    if (lane == 0) { wnum[wave] = num; wcnt[wave] = cnt; }
    __syncthreads();
    if (t == 0) {
        const float n = wnum[0] + wnum[1] + wnum[2] + wnum[3];
        const int   c = wcnt[0] + wcnt[1] + wcnt[2] + wcnt[3];
        atomicAdd(acc_num, (double)n);
        atomicAdd(acc_cnt, (unsigned long long)c);
    }
}

__global__ void finalize_kernel(const double* __restrict__ acc_num,
                                const unsigned long long* __restrict__ acc_cnt,
                                float* __restrict__ out)
{
    const double c = (double)(*acc_cnt);
    out[0] = (float)((*acc_num) / c / 32.0);
}

extern "C" void kernel_launch(void* const* d_in, const int* in_sizes, int n_in,
                              void* d_out, int out_size, void* d_ws, size_t ws_size,
                              hipStream_t stream)
{
    const float* fake = (const float*)d_in[0];
    const float* real = (const float*)d_in[1];
    float* out = (float*)d_out;

    double* acc_num             = (double*)d_ws;
    unsigned long long* acc_cnt = (unsigned long long*)((char*)d_ws + 8);

    hipMemsetAsync(d_ws, 0, 16, stream);
    sobel_loss_kernel<<<NBLK, 256, 0, stream>>>(fake, real, acc_num, acc_cnt);
    finalize_kernel<<<1, 1, 0, stream>>>(acc_num, acc_cnt, out);
}